// Round 20
// baseline (448.149 us; speedup 1.0000x reference)
//
#include <hip/hip_runtime.h>
#include <hip/hip_cooperative_groups.h>

namespace cg = cooperative_groups;

#define C 16
#define TAPS 27
#define NCONV 17
#define LISTCAP 98304
#define NPAIR 14

typedef _Float16 half8 __attribute__((ext_vector_type(8)));
typedef _Float16 half4 __attribute__((ext_vector_type(4)));
typedef float f32x4 __attribute__((ext_vector_type(4)));

// ---- prep: weights, m48, counts + inv=-1 init ----
__global__ void prep_kernel(const int* __restrict__ mask_idx, const float* __restrict__ W,
                            _Float16* __restrict__ Wh, int* __restrict__ counts,
                            float* __restrict__ m48, int* __restrict__ inv) {
    int b = blockIdx.x;
    if (b < 476) {
        int i = b * 256 + threadIdx.x;
        const int total = NCONV * NPAIR * 64 * 8;
        if (i < total) {
            int j = i & 7;
            int lane = (i >> 3) & 63;
            int p = (i >> 9) % NPAIR;
            int l = (i >> 9) / NPAIR;
            int co = lane & 15;
            int g = lane >> 4;
            int k = 8 * g + j;
            int ci = k & 15;
            int tap = 2 * p + (k >> 4);
            float val = (tap < TAPS) ? W[((l * C + co) * C + ci) * TAPS + tap] : 0.f;
            Wh[i] = (_Float16)val;
        }
    } else if (b < 476 + 432) {
        int i = (b - 476) * 256 + threadIdx.x;  // 110592 m48 voxels
        int xx = i % 48, yy = (i / 48) % 48, zc = i / (48 * 48);
        float m = 0.f;
        for (int dz = 0; dz < 3; dz++) {
            int z2 = 2 * zc - 1 + dz;
            if ((unsigned)z2 >= 96u) continue;
            for (int dy = 0; dy < 3; dy++) {
                int y2 = 2 * yy - 1 + dy;
                if ((unsigned)y2 >= 96u) continue;
                for (int dx = 0; dx < 3; dx++) {
                    int x2 = 2 * xx - 1 + dx;
                    if ((unsigned)x2 >= 96u) continue;
                    if (mask_idx[((long)z2 * 96 + y2) * 96 + x2] == 0) m = 1.f;
                }
            }
        }
        m48[i] = m;
    } else {
        int v = (b - 476 - 432) * 256 + threadIdx.x;
        inv[v] = -1;
        int act = (mask_idx[v] == 0);
        unsigned long long bl = __ballot(act);
        __shared__ int wsum[4];
        int wid = threadIdx.x >> 6, lane = threadIdx.x & 63;
        if (lane == 0) wsum[wid] = __popcll(bl);
        __syncthreads();
        if (threadIdx.x == 0) counts[b - 476 - 432] = wsum[0] + wsum[1] + wsum[2] + wsum[3];
    }
}

__global__ void scan_kernel(const int* __restrict__ counts, int* __restrict__ offsets,
                            int* __restrict__ nact, int nb) {
    __shared__ int s[256];
    int t = threadIdx.x;
    const int CH = (nb + 255) / 256;
    int base = t * CH, sum = 0;
    for (int j = 0; j < CH; j++)
        if (base + j < nb) sum += counts[base + j];
    s[t] = sum;
    __syncthreads();
    for (int off = 1; off < 256; off <<= 1) {
        int v = (t >= off) ? s[t - off] : 0;
        __syncthreads();
        s[t] += v;
        __syncthreads();
    }
    int run = s[t] - sum;
    for (int j = 0; j < CH; j++) {
        if (base + j < nb) {
            offsets[base + j] = run;
            run += counts[base + j];
        }
    }
    if (t == 255) *nact = s[255];
}

// ---- scatter (list + inv) + pools (m24 3^3, m12 7^3, m6 15^3 — from m48) ----
__global__ void scatter_kernel(const int* __restrict__ mi, const int* __restrict__ offsets,
                               int* __restrict__ list, int* __restrict__ inv, int cap,
                               const float* __restrict__ m48, float* __restrict__ m24,
                               float* __restrict__ m12, float* __restrict__ m6) {
    int b = blockIdx.x;
    int tid = threadIdx.x;
    if (b < 3456) {
        int i = b * 256 + tid;
        int act = (mi[i] == 0);
        unsigned long long bl = __ballot(act);
        __shared__ int wsum[4];
        int wid = tid >> 6, lane = tid & 63;
        if (lane == 0) wsum[wid] = __popcll(bl);
        __syncthreads();
        int wbase = 0;
        for (int w = 0; w < wid; w++) wbase += wsum[w];
        int prefix = __popcll(bl & ((1ull << lane) - 1));
        if (act) {
            int pos = offsets[b] + wbase + prefix;
            if (pos < cap) {
                list[pos] = i;
                inv[i] = pos;
            }
        }
    } else if (b < 3456 + 54) {
        int i = (b - 3456) * 256 + tid;
        if (i < 24 * 24 * 24) {
            int x = i % 24, y = (i / 24) % 24, z = i / (24 * 24);
            float m = 0.f;
            for (int dz = 0; dz < 3; dz++) {
                int zz = 2 * z - 1 + dz;
                if ((unsigned)zz >= 48u) continue;
                for (int dy = 0; dy < 3; dy++) {
                    int yy = 2 * y - 1 + dy;
                    if ((unsigned)yy >= 48u) continue;
                    for (int dx = 0; dx < 3; dx++) {
                        int xx = 2 * x - 1 + dx;
                        if ((unsigned)xx >= 48u) continue;
                        m = fmaxf(m, m48[((long)zz * 48 + yy) * 48 + xx]);
                    }
                }
            }
            m24[i] = m;
        }
    } else if (b < 3456 + 54 + 432) {
        int wv = (b - 3456 - 54) * 4 + (tid >> 6);
        int lane = tid & 63;
        int x = wv % 12, y = (wv / 12) % 12, z = wv / 144;
        float m = 0.f;
        for (int k = lane; k < 343; k += 64) {
            int dz = k / 49, r = k % 49, dy = r / 7, dx = r % 7;
            int zz = 4 * z - 3 + dz, yy = 4 * y - 3 + dy, xx = 4 * x - 3 + dx;
            if ((unsigned)zz < 48u && (unsigned)yy < 48u && (unsigned)xx < 48u)
                m = fmaxf(m, m48[((long)zz * 48 + yy) * 48 + xx]);
        }
        for (int off = 32; off; off >>= 1) m = fmaxf(m, __shfl_xor(m, off));
        if (lane == 0 && wv < 1728) m12[wv] = m;
    } else {
        int wv = (b - 3456 - 54 - 432) * 4 + (tid >> 6);
        int lane = tid & 63;
        int x = wv % 6, y = (wv / 6) % 6, z = wv / 36;
        float m = 0.f;
        for (int k = lane; k < 3375; k += 64) {
            int dz = k / 225, r = k % 225, dy = r / 15, dx = r % 15;
            int zz = 8 * z - 7 + dz, yy = 8 * y - 7 + dy, xx = 8 * x - 7 + dx;
            if ((unsigned)zz < 48u && (unsigned)yy < 48u && (unsigned)xx < 48u)
                m = fmaxf(m, m48[((long)zz * 48 + yy) * 48 + xx]);
        }
        for (int off = 32; off; off >>= 1) m = fmaxf(m, __shfl_xor(m, off));
        if (lane == 0 && wv < 216) m6[wv] = m;
    }
}

// ---- compactx v2: dense-side coalesced transpose + nbr table ----
__global__ void compactx_kernel(const float* __restrict__ x, const int* __restrict__ list,
                                const int* __restrict__ nact, const int* __restrict__ inv,
                                _Float16* __restrict__ Xc, int* __restrict__ nbr) {
    const int n96 = 96 * 96 * 96;
    int b = blockIdx.x;
    if (b < 3456) {
        int v = b * 256 + threadIdx.x;
        int idx = inv[v];
        half8 h0, h1;
#pragma unroll
        for (int c = 0; c < 8; c++) h0[c] = (_Float16)x[(long)c * n96 + v];
#pragma unroll
        for (int c = 0; c < 8; c++) h1[c] = (_Float16)x[(long)(c + 8) * n96 + v];
        if (idx >= 0) {
            half8* dp = reinterpret_cast<half8*>(Xc + (long)idx * C);
            dp[0] = h0;
            dp[1] = h1;
        }
    } else {
        int nv = *nact;
        if (nv > LISTCAP) nv = LISTCAP;
        int s = (b - 3456) * 256 + threadIdx.x;
        if (s >= nv) return;
        int v = list[s];
        int xx = v % 96, yy = (v / 96) % 96, zz = v / (96 * 96);
        for (int t = 0; t < TAPS; t++) {
            int kz = t / 9, ky = (t / 3) % 3, kx = t % 3;
            int z2 = zz - 1 + kz, y2 = yy - 1 + ky, x2 = xx - 1 + kx;
            int idx = -1;
            if ((unsigned)z2 < 96u && (unsigned)y2 < 96u && (unsigned)x2 < 96u)
                idx = inv[((long)z2 * 96 + y2) * 96 + x2];
            nbr[t * LISTCAP + s] = idx;
        }
    }
}

// ---- sparse conv over compacted activations ----
__global__ __launch_bounds__(256) void sconv_kernel(
    const _Float16* __restrict__ Ain, _Float16* __restrict__ Aout,
    const int* __restrict__ nbr, const int* __restrict__ nact,
    const _Float16* __restrict__ Whl, const float* __restrict__ bs,
    const float* __restrict__ bb) {
    int nv = *nact;
    if (nv > LISTCAP) nv = LISTCAP;
    int tile = blockIdx.x * 4 + (threadIdx.x >> 6);
    if (tile * 16 >= nv) return;

    int lane = threadIdx.x & 63;
    int col = lane & 15;
    int g = lane >> 4;
    int s = tile * 16 + col;
    bool val = s < nv;

    const half8* wf = reinterpret_cast<const half8*>(Whl);
    half8 a[NPAIR];
#pragma unroll
    for (int p = 0; p < NPAIR; p++) a[p] = wf[p * 64 + lane];

    int half_off = (g & 1) * 8;
    int tg = g >> 1;

    f32x4 acc = {0.f, 0.f, 0.f, 0.f};
#pragma unroll
    for (int p = 0; p < NPAIR; p++) {
        int tap = 2 * p + tg;
        if (tap > TAPS - 1) tap = TAPS - 1;
        int idx = -1;
        if (val) idx = nbr[tap * LISTCAP + s];
        half8 b = {};
        if (idx >= 0) b = *reinterpret_cast<const half8*>(Ain + (long)idx * C + half_off);
        acc = __builtin_amdgcn_mfma_f32_16x16x32_f16(a[p], b, acc, 0, 0, 0);
    }

    if (val) {
        int cob = g * 4;
        half4 r;
#pragma unroll
        for (int j = 0; j < 4; j++)
            r[j] = (_Float16)fmaxf(acc[j] * bs[cob + j] + bb[cob + j], 0.f);
        *reinterpret_cast<half4*>(Aout + (long)s * C + cob) = r;
    }
}

// ---- down 96->48 via inv; writes dense 48^3 NDHWC ----
__global__ __launch_bounds__(256) void dconv_inv_kernel(
    const _Float16* __restrict__ Ain, _Float16* __restrict__ out,
    const float* __restrict__ mask, const int* __restrict__ inv,
    const _Float16* __restrict__ Whl, const float* __restrict__ bs,
    const float* __restrict__ bb) {
    const int n = 48 * 48 * 48;
    int tile = blockIdx.x * 4 + (threadIdx.x >> 6);
    if (tile * 16 >= n) return;
    int lane = threadIdx.x & 63;
    int col = lane & 15;
    int g = lane >> 4;
    int v = tile * 16 + col;
    int x = v % 48, y = (v / 48) % 48, z = v / (48 * 48);

    const half8* wf = reinterpret_cast<const half8*>(Whl);
    half8 a[NPAIR];
#pragma unroll
    for (int p = 0; p < NPAIR; p++) a[p] = wf[p * 64 + lane];
    int half_off = (g & 1) * 8;
    int tg = g >> 1;

    f32x4 acc = {0.f, 0.f, 0.f, 0.f};
#pragma unroll
    for (int p = 0; p < NPAIR; p++) {
        int tap = 2 * p + tg;
        if (tap > TAPS - 1) tap = TAPS - 1;
        int kz = tap / 9, ky = (tap / 3) % 3, kx = tap % 3;
        int zz = 2 * z - 1 + kz, yy = 2 * y - 1 + ky, xx = 2 * x - 1 + kx;
        int idx = -1;
        if ((unsigned)zz < 96u && (unsigned)yy < 96u && (unsigned)xx < 96u)
            idx = inv[((long)zz * 96 + yy) * 96 + xx];
        half8 b = {};
        if (idx >= 0) b = *reinterpret_cast<const half8*>(Ain + (long)idx * C + half_off);
        acc = __builtin_amdgcn_mfma_f32_16x16x32_f16(a[p], b, acc, 0, 0, 0);
    }

    float mk = mask[v];
    int cob = g * 4;
    half4 r;
#pragma unroll
    for (int j = 0; j < 4; j++)
        r[j] = (_Float16)(fmaxf(acc[j] * bs[cob + j] + bb[cob + j], 0.f) * mk);
    *reinterpret_cast<half4*>(out + (long)v * C + cob) = r;
}

// ---- dense MFMA conv tile (shared by mconv and the cooperative tail) ----
__device__ __forceinline__ void conv_tile(
    int w, int lane, int ntiles, int n, int Din, int Dout, int stride,
    const _Float16* __restrict__ src, const float* __restrict__ mask,
    const _Float16* __restrict__ Whl, const float* __restrict__ bsl,
    const float* __restrict__ bbl, _Float16* __restrict__ dsth,
    float* __restrict__ dstf) {
    if (w >= ntiles) return;
    int col = lane & 15, g = lane >> 4;
    int s = w * 16 + col;
    bool val = s < n;
    int v = val ? s : 0;
    int x = v % Dout, y = (v / Dout) % Dout, z = v / (Dout * Dout);
    const half8* wf = reinterpret_cast<const half8*>(Whl);
    half8 a[NPAIR];
#pragma unroll
    for (int p = 0; p < NPAIR; p++) a[p] = wf[p * 64 + lane];
    int ho = (g & 1) * 8, tg = g >> 1;
    f32x4 acc = {0.f, 0.f, 0.f, 0.f};
#pragma unroll
    for (int p = 0; p < NPAIR; p++) {
        int tap = 2 * p + tg;
        if (tap > TAPS - 1) tap = TAPS - 1;
        int kz = tap / 9, ky = (tap / 3) % 3, kx = tap % 3;
        int zz = stride * z - 1 + kz;
        int yy = stride * y - 1 + ky;
        int xx = stride * x - 1 + kx;
        bool ok = val && ((unsigned)zz < (unsigned)Din) && ((unsigned)yy < (unsigned)Din) &&
                  ((unsigned)xx < (unsigned)Din);
        half8 b = {};
        if (ok)
            b = *reinterpret_cast<const half8*>(src + (long)((zz * Din + yy) * Din + xx) * C + ho);
        acc = __builtin_amdgcn_mfma_f32_16x16x32_f16(a[p], b, acc, 0, 0, 0);
    }
    if (val) {
        float mk = mask[v];
        int cob = g * 4;
        half4 r;
#pragma unroll
        for (int j = 0; j < 4; j++) {
            float t = fmaxf(acc[j] * bsl[cob + j] + bbl[cob + j], 0.f) * mk;
            r[j] = (_Float16)t;
            if (dstf) dstf[(long)(cob + j) * n + v] = t;
        }
        if (dsth) *reinterpret_cast<half4*>(dsth + (long)v * C + cob) = r;
    }
}

// ---- dense conv launch wrapper (48 level) ----
template <bool WF32>
__global__ __launch_bounds__(256) void mconv_kernel(
    const _Float16* __restrict__ in, _Float16* __restrict__ out,
    const float* __restrict__ mask, const _Float16* __restrict__ Whl,
    const float* __restrict__ bs, const float* __restrict__ bb,
    int D, float* __restrict__ outf) {
    int n = D * D * D;
    int w = blockIdx.x * 4 + (threadIdx.x >> 6);
    conv_tile(w, threadIdx.x & 63, (n + 15) / 16, n, D, D, 1, in, mask, Whl, bs, bb, out,
              WF32 ? outf : nullptr);
}

// ---- cooperative tail: layers 5..16 (24, 12, 6 levels) ----
__global__ __launch_bounds__(256) void tail24_kernel(
    const _Float16* __restrict__ P48, const float* __restrict__ m24,
    const float* __restrict__ m12, const float* __restrict__ m6,
    const _Float16* __restrict__ Wh, const float* __restrict__ bs,
    const float* __restrict__ bb, _Float16* __restrict__ T0, _Float16* __restrict__ T1,
    _Float16* __restrict__ T2, _Float16* __restrict__ T3, _Float16* __restrict__ G0,
    _Float16* __restrict__ G1, float* __restrict__ out2, float* __restrict__ out3,
    float* __restrict__ out4) {
    cg::grid_group grid = cg::this_grid();
    int lane = threadIdx.x & 63;
    int w = blockIdx.x * 4 + (threadIdx.x >> 6);  // 0..863
    auto WLp = [&](int l) { return Wh + (long)l * NPAIR * 64 * 8; };

    conv_tile(w, lane, 864, 13824, 48, 24, 2, P48, m24, WLp(5), bs + 5 * C, bb + 5 * C, T0, nullptr);
    grid.sync();
    conv_tile(w, lane, 864, 13824, 24, 24, 1, T0, m24, WLp(6), bs + 6 * C, bb + 6 * C, T1, nullptr);
    grid.sync();
    conv_tile(w, lane, 864, 13824, 24, 24, 1, T1, m24, WLp(7), bs + 7 * C, bb + 7 * C, T0, nullptr);
    grid.sync();
    conv_tile(w, lane, 864, 13824, 24, 24, 1, T0, m24, WLp(8), bs + 8 * C, bb + 8 * C, T1, out2);
    grid.sync();
    conv_tile(w, lane, 108, 1728, 24, 12, 2, T1, m12, WLp(9), bs + 9 * C, bb + 9 * C, T2, nullptr);
    grid.sync();
    conv_tile(w, lane, 108, 1728, 12, 12, 1, T2, m12, WLp(10), bs + 10 * C, bb + 10 * C, T3, nullptr);
    grid.sync();
    conv_tile(w, lane, 108, 1728, 12, 12, 1, T3, m12, WLp(11), bs + 11 * C, bb + 11 * C, T2, nullptr);
    grid.sync();
    conv_tile(w, lane, 108, 1728, 12, 12, 1, T2, m12, WLp(12), bs + 12 * C, bb + 12 * C, T3, out3);
    grid.sync();
    conv_tile(w, lane, 14, 216, 12, 6, 2, T3, m6, WLp(13), bs + 13 * C, bb + 13 * C, G0, nullptr);
    grid.sync();
    conv_tile(w, lane, 14, 216, 6, 6, 1, G0, m6, WLp(14), bs + 14 * C, bb + 14 * C, G1, nullptr);
    grid.sync();
    conv_tile(w, lane, 14, 216, 6, 6, 1, G1, m6, WLp(15), bs + 15 * C, bb + 15 * C, G0, nullptr);
    grid.sync();
    conv_tile(w, lane, 14, 216, 6, 6, 1, G0, m6, WLp(16), bs + 16 * C, bb + 16 * C, nullptr, out4);
}

extern "C" void kernel_launch(void* const* d_in, const int* in_sizes, int n_in,
                              void* d_out, int out_size, void* d_ws, size_t ws_size,
                              hipStream_t stream) {
    const float* x = (const float*)d_in[0];
    const int* mask_idx = (const int*)d_in[1];
    const float* W = (const float*)d_in[2];
    const float* bs = (const float*)d_in[3];
    const float* bb = (const float*)d_in[4];
    float* out = (float*)d_out;

    const int n96 = 96 * 96 * 96;
    const int n48 = 48 * 48 * 48;
    const int n24 = 24 * 24 * 24;
    const int n12 = 12 * 12 * 12;
    const int n6 = 6 * 6 * 6;
    const int NB = 3456;

    float* m48 = (float*)d_ws;
    float* m24 = m48 + n48;
    float* m12 = m24 + n24;
    float* m6 = m12 + n12;
    _Float16* Wh = (_Float16*)(m6 + n6);
    int* list = (int*)(Wh + (long)NCONV * NPAIR * 64 * 8);
    int* counts = list + LISTCAP;
    int* offsets = counts + NB;
    int* nact = offsets + NB;
    int* inv = nact + 1;
    int* nbr = inv + n96;
    _Float16* Xc = (_Float16*)(nbr + TAPS * LISTCAP);
    _Float16* A1 = Xc + (long)LISTCAP * C;
    _Float16* A2 = A1 + (long)LISTCAP * C;
    _Float16* P0h = A2 + (long)LISTCAP * C;
    _Float16* P1h = P0h + (long)n48 * C;
    // tail buffers overlay P0h (free after L4)
    _Float16* T0 = P0h;
    _Float16* T1 = T0 + (long)n24 * C;
    _Float16* T2 = T1 + (long)n24 * C;
    _Float16* T3 = T2 + (long)n12 * C;
    _Float16* G0 = T3 + (long)n12 * C;
    _Float16* G1 = G0 + (long)n6 * C;

    // 1. prep
    hipLaunchKernelGGL(prep_kernel, dim3(476 + 432 + 3456), dim3(256), 0, stream,
                       mask_idx, W, Wh, counts, m48, inv);
    // 2. scan
    hipLaunchKernelGGL(scan_kernel, dim3(1), dim3(256), 0, stream, counts, offsets, nact, NB);
    // 3. scatter + pools
    hipLaunchKernelGGL(scatter_kernel, dim3(3456 + 54 + 432 + 54), dim3(256), 0, stream,
                       mask_idx, offsets, list, inv, LISTCAP, m48, m24, m12, m6);
    // 4. compactx (dense transpose + nbr)
    hipLaunchKernelGGL(compactx_kernel, dim3(3456 + LISTCAP / 256), dim3(256), 0, stream,
                       x, list, nact, inv, Xc, nbr);

    auto mblk = [&](long nvox) { return dim3((unsigned)((nvox + 63) / 64)); };
    auto WL = [&](int l) { return Wh + (long)l * NPAIR * 64 * 8; };

    // 5-6. sparse 96 level
    hipLaunchKernelGGL(sconv_kernel, mblk(LISTCAP), dim3(256), 0, stream,
                       Xc, A1, nbr, nact, WL(0), bs, bb);
    hipLaunchKernelGGL(sconv_kernel, mblk(LISTCAP), dim3(256), 0, stream,
                       A1, A2, nbr, nact, WL(1), bs + C, bb + C);
    // 7. down 96->48
    hipLaunchKernelGGL(dconv_inv_kernel, mblk(n48), dim3(256), 0, stream,
                       A2, P1h, m48, inv, WL(2), bs + 2 * C, bb + 2 * C);
    // 8-9. 48 subm; L4 dual-writes net1
    hipLaunchKernelGGL((mconv_kernel<false>), mblk(n48), dim3(256), 0, stream,
                       P1h, P0h, m48, WL(3), bs + 3 * C, bb + 3 * C, 48, (float*)nullptr);
    hipLaunchKernelGGL((mconv_kernel<true>), mblk(n48), dim3(256), 0, stream,
                       P0h, P1h, m48, WL(4), bs + 4 * C, bb + 4 * C, 48, out);
    // 10. cooperative tail: layers 5..16 (net2, net3, net4)
    {
        const _Float16* a_P48 = P1h;
        const float* a_m24 = m24;
        const float* a_m12 = m12;
        const float* a_m6 = m6;
        const _Float16* a_Wh = Wh;
        const float* a_bs = bs;
        const float* a_bb = bb;
        _Float16* a_T0 = T0;
        _Float16* a_T1 = T1;
        _Float16* a_T2 = T2;
        _Float16* a_T3 = T3;
        _Float16* a_G0 = G0;
        _Float16* a_G1 = G1;
        float* a_out2 = out + (long)C * n48;
        float* a_out3 = out + (long)C * (n48 + n24);
        float* a_out4 = out + (long)C * (n48 + n24 + n12);
        void* args[] = {&a_P48, &a_m24, &a_m12, &a_m6, &a_Wh, &a_bs, &a_bb,
                        &a_T0, &a_T1, &a_T2, &a_T3, &a_G0, &a_G1,
                        &a_out2, &a_out3, &a_out4};
        hipLaunchCooperativeKernel((const void*)tail24_kernel, dim3(216), dim3(256), args, 0,
                                   stream);
    }
}

// Round 21
// 198.695 us; speedup vs baseline: 2.2555x; 2.2555x over previous
//
#include <hip/hip_runtime.h>

#define C 16
#define TAPS 27
#define NCONV 17
#define LISTCAP 98304
#define NPAIR 14

typedef _Float16 half8 __attribute__((ext_vector_type(8)));
typedef _Float16 half4 __attribute__((ext_vector_type(4)));
typedef float f32x4 __attribute__((ext_vector_type(4)));

// ---- prep: weights, m48, counts + inv=-1 init ----
// Wh[l][pair][lane][8]: lane co=lane&15, g=lane>>4; k=8g+j; ci=k&15; tap=2p+(k>>4).
__global__ void prep_kernel(const int* __restrict__ mask_idx, const float* __restrict__ W,
                            _Float16* __restrict__ Wh, int* __restrict__ counts,
                            float* __restrict__ m48, int* __restrict__ inv) {
    int b = blockIdx.x;
    if (b < 476) {
        int i = b * 256 + threadIdx.x;
        const int total = NCONV * NPAIR * 64 * 8;
        if (i < total) {
            int j = i & 7;
            int lane = (i >> 3) & 63;
            int p = (i >> 9) % NPAIR;
            int l = (i >> 9) / NPAIR;
            int co = lane & 15;
            int g = lane >> 4;
            int k = 8 * g + j;
            int ci = k & 15;
            int tap = 2 * p + (k >> 4);
            float val = (tap < TAPS) ? W[((l * C + co) * C + ci) * TAPS + tap] : 0.f;
            Wh[i] = (_Float16)val;
        }
    } else if (b < 476 + 432) {
        // m48: thread per voxel, 3^3 window over mask_idx at [2c-1, 2c+1]
        int i = (b - 476) * 256 + threadIdx.x;  // 432*256 == 110592
        int xx = i % 48, yy = (i / 48) % 48, zc = i / (48 * 48);
        float m = 0.f;
        for (int dz = 0; dz < 3; dz++) {
            int z2 = 2 * zc - 1 + dz;
            if ((unsigned)z2 >= 96u) continue;
            for (int dy = 0; dy < 3; dy++) {
                int y2 = 2 * yy - 1 + dy;
                if ((unsigned)y2 >= 96u) continue;
                for (int dx = 0; dx < 3; dx++) {
                    int x2 = 2 * xx - 1 + dx;
                    if ((unsigned)x2 >= 96u) continue;
                    if (mask_idx[((long)z2 * 96 + y2) * 96 + x2] == 0) m = 1.f;
                }
            }
        }
        m48[i] = m;
    } else {
        // counts + inv init (3456 blocks)
        int v = (b - 476 - 432) * 256 + threadIdx.x;
        inv[v] = -1;
        int act = (mask_idx[v] == 0);
        unsigned long long bl = __ballot(act);
        __shared__ int wsum[4];
        int wid = threadIdx.x >> 6, lane = threadIdx.x & 63;
        if (lane == 0) wsum[wid] = __popcll(bl);
        __syncthreads();
        if (threadIdx.x == 0) counts[b - 476 - 432] = wsum[0] + wsum[1] + wsum[2] + wsum[3];
    }
}

__global__ void scan_kernel(const int* __restrict__ counts, int* __restrict__ offsets,
                            int* __restrict__ nact, int nb) {
    __shared__ int s[256];
    int t = threadIdx.x;
    const int CH = (nb + 255) / 256;
    int base = t * CH, sum = 0;
    for (int j = 0; j < CH; j++)
        if (base + j < nb) sum += counts[base + j];
    s[t] = sum;
    __syncthreads();
    for (int off = 1; off < 256; off <<= 1) {
        int v = (t >= off) ? s[t - off] : 0;
        __syncthreads();
        s[t] += v;
        __syncthreads();
    }
    int run = s[t] - sum;
    for (int j = 0; j < CH; j++) {
        if (base + j < nb) {
            offsets[base + j] = run;
            run += counts[base + j];
        }
    }
    if (t == 255) *nact = s[255];
}

// ---- scatter (list + inv) + pools (m24 3^3, m12 7^3, m6 15^3 — from m48) ----
__global__ void scatter_kernel(const int* __restrict__ mi, const int* __restrict__ offsets,
                               int* __restrict__ list, int* __restrict__ inv, int cap,
                               const float* __restrict__ m48, float* __restrict__ m24,
                               float* __restrict__ m12, float* __restrict__ m6) {
    int b = blockIdx.x;
    int tid = threadIdx.x;
    if (b < 3456) {
        int i = b * 256 + tid;
        int act = (mi[i] == 0);
        unsigned long long bl = __ballot(act);
        __shared__ int wsum[4];
        int wid = tid >> 6, lane = tid & 63;
        if (lane == 0) wsum[wid] = __popcll(bl);
        __syncthreads();
        int wbase = 0;
        for (int w = 0; w < wid; w++) wbase += wsum[w];
        int prefix = __popcll(bl & ((1ull << lane) - 1));
        if (act) {
            int pos = offsets[b] + wbase + prefix;
            if (pos < cap) {
                list[pos] = i;
                inv[i] = pos;
            }
        }
    } else if (b < 3456 + 54) {  // m24
        int i = (b - 3456) * 256 + tid;
        if (i < 24 * 24 * 24) {
            int x = i % 24, y = (i / 24) % 24, z = i / (24 * 24);
            float m = 0.f;
            for (int dz = 0; dz < 3; dz++) {
                int zz = 2 * z - 1 + dz;
                if ((unsigned)zz >= 48u) continue;
                for (int dy = 0; dy < 3; dy++) {
                    int yy = 2 * y - 1 + dy;
                    if ((unsigned)yy >= 48u) continue;
                    for (int dx = 0; dx < 3; dx++) {
                        int xx = 2 * x - 1 + dx;
                        if ((unsigned)xx >= 48u) continue;
                        m = fmaxf(m, m48[((long)zz * 48 + yy) * 48 + xx]);
                    }
                }
            }
            m24[i] = m;
        }
    } else if (b < 3456 + 54 + 432) {  // m12: wave/voxel, 7^3 over m48
        int wv = (b - 3456 - 54) * 4 + (tid >> 6);
        int lane = tid & 63;
        int x = wv % 12, y = (wv / 12) % 12, z = wv / 144;
        float m = 0.f;
        for (int k = lane; k < 343; k += 64) {
            int dz = k / 49, r = k % 49, dy = r / 7, dx = r % 7;
            int zz = 4 * z - 3 + dz, yy = 4 * y - 3 + dy, xx = 4 * x - 3 + dx;
            if ((unsigned)zz < 48u && (unsigned)yy < 48u && (unsigned)xx < 48u)
                m = fmaxf(m, m48[((long)zz * 48 + yy) * 48 + xx]);
        }
        for (int off = 32; off; off >>= 1) m = fmaxf(m, __shfl_xor(m, off));
        if (lane == 0 && wv < 1728) m12[wv] = m;
    } else {  // m6: wave/voxel, 15^3 over m48
        int wv = (b - 3456 - 54 - 432) * 4 + (tid >> 6);
        int lane = tid & 63;
        int x = wv % 6, y = (wv / 6) % 6, z = wv / 36;
        float m = 0.f;
        for (int k = lane; k < 3375; k += 64) {
            int dz = k / 225, r = k % 225, dy = r / 15, dx = r % 15;
            int zz = 8 * z - 7 + dz, yy = 8 * y - 7 + dy, xx = 8 * x - 7 + dx;
            if ((unsigned)zz < 48u && (unsigned)yy < 48u && (unsigned)xx < 48u)
                m = fmaxf(m, m48[((long)zz * 48 + yy) * 48 + xx]);
        }
        for (int off = 32; off; off >>= 1) m = fmaxf(m, __shfl_xor(m, off));
        if (lane == 0 && wv < 216) m6[wv] = m;
    }
}

// ---- compactx v2: dense-side coalesced transpose + nbr table ----
__global__ void compactx_kernel(const float* __restrict__ x, const int* __restrict__ list,
                                const int* __restrict__ nact, const int* __restrict__ inv,
                                _Float16* __restrict__ Xc, int* __restrict__ nbr) {
    const int n96 = 96 * 96 * 96;
    int b = blockIdx.x;
    if (b < 3456) {
        int v = b * 256 + threadIdx.x;
        int idx = inv[v];
        if (idx >= 0) {
            half8 h0, h1;
#pragma unroll
            for (int c = 0; c < 8; c++) h0[c] = (_Float16)x[(long)c * n96 + v];
#pragma unroll
            for (int c = 0; c < 8; c++) h1[c] = (_Float16)x[(long)(c + 8) * n96 + v];
            half8* dp = reinterpret_cast<half8*>(Xc + (long)idx * C);
            dp[0] = h0;
            dp[1] = h1;
        }
    } else {
        int nv = *nact;
        if (nv > LISTCAP) nv = LISTCAP;
        int s = (b - 3456) * 256 + threadIdx.x;
        if (s >= nv) return;
        int v = list[s];
        int xx = v % 96, yy = (v / 96) % 96, zz = v / (96 * 96);
        for (int t = 0; t < TAPS; t++) {
            int kz = t / 9, ky = (t / 3) % 3, kx = t % 3;
            int z2 = zz - 1 + kz, y2 = yy - 1 + ky, x2 = xx - 1 + kx;
            int idx = -1;
            if ((unsigned)z2 < 96u && (unsigned)y2 < 96u && (unsigned)x2 < 96u)
                idx = inv[((long)z2 * 96 + y2) * 96 + x2];
            nbr[t * LISTCAP + s] = idx;
        }
    }
}

// ---- sparse conv over compacted activations (nbr-indexed gather) ----
__global__ __launch_bounds__(256) void sconv_kernel(
    const _Float16* __restrict__ Ain, _Float16* __restrict__ Aout,
    const int* __restrict__ nbr, const int* __restrict__ nact,
    const _Float16* __restrict__ Whl, const float* __restrict__ bs,
    const float* __restrict__ bb) {
    int nv = *nact;
    if (nv > LISTCAP) nv = LISTCAP;
    int tile = blockIdx.x * 4 + (threadIdx.x >> 6);
    if (tile * 16 >= nv) return;

    int lane = threadIdx.x & 63;
    int col = lane & 15;
    int g = lane >> 4;
    int s = tile * 16 + col;
    bool val = s < nv;

    const half8* wf = reinterpret_cast<const half8*>(Whl);
    half8 a[NPAIR];
#pragma unroll
    for (int p = 0; p < NPAIR; p++) a[p] = wf[p * 64 + lane];

    int half_off = (g & 1) * 8;
    int tg = g >> 1;

    f32x4 acc = {0.f, 0.f, 0.f, 0.f};
#pragma unroll
    for (int p = 0; p < NPAIR; p++) {
        int tap = 2 * p + tg;
        if (tap > TAPS - 1) tap = TAPS - 1;  // dummy half: weights are 0
        int idx = -1;
        if (val) idx = nbr[tap * LISTCAP + s];
        half8 b = {};
        if (idx >= 0) b = *reinterpret_cast<const half8*>(Ain + (long)idx * C + half_off);
        acc = __builtin_amdgcn_mfma_f32_16x16x32_f16(a[p], b, acc, 0, 0, 0);
    }

    if (val) {
        int cob = g * 4;
        half4 r;
#pragma unroll
        for (int j = 0; j < 4; j++)
            r[j] = (_Float16)fmaxf(acc[j] * bs[cob + j] + bb[cob + j], 0.f);
        *reinterpret_cast<half4*>(Aout + (long)s * C + cob) = r;
    }
}

// ---- down 96->48 reading compacted A via inv; writes dense 48^3 NDHWC ----
__global__ __launch_bounds__(256) void dconv_inv_kernel(
    const _Float16* __restrict__ Ain, _Float16* __restrict__ out,
    const float* __restrict__ mask, const int* __restrict__ inv,
    const _Float16* __restrict__ Whl, const float* __restrict__ bs,
    const float* __restrict__ bb) {
    const int n = 48 * 48 * 48;
    int tile = blockIdx.x * 4 + (threadIdx.x >> 6);
    if (tile * 16 >= n) return;
    int lane = threadIdx.x & 63;
    int col = lane & 15;
    int g = lane >> 4;
    int v = tile * 16 + col;  // < n always
    int x = v % 48, y = (v / 48) % 48, z = v / (48 * 48);

    const half8* wf = reinterpret_cast<const half8*>(Whl);
    half8 a[NPAIR];
#pragma unroll
    for (int p = 0; p < NPAIR; p++) a[p] = wf[p * 64 + lane];
    int half_off = (g & 1) * 8;
    int tg = g >> 1;

    f32x4 acc = {0.f, 0.f, 0.f, 0.f};
#pragma unroll
    for (int p = 0; p < NPAIR; p++) {
        int tap = 2 * p + tg;
        if (tap > TAPS - 1) tap = TAPS - 1;
        int kz = tap / 9, ky = (tap / 3) % 3, kx = tap % 3;
        int zz = 2 * z - 1 + kz, yy = 2 * y - 1 + ky, xx = 2 * x - 1 + kx;
        int idx = -1;
        if ((unsigned)zz < 96u && (unsigned)yy < 96u && (unsigned)xx < 96u)
            idx = inv[((long)zz * 96 + yy) * 96 + xx];
        half8 b = {};
        if (idx >= 0) b = *reinterpret_cast<const half8*>(Ain + (long)idx * C + half_off);
        acc = __builtin_amdgcn_mfma_f32_16x16x32_f16(a[p], b, acc, 0, 0, 0);
    }

    float mk = mask[v];
    int cob = g * 4;
    half4 r;
#pragma unroll
    for (int j = 0; j < 4; j++)
        r[j] = (_Float16)(fmaxf(acc[j] * bs[cob + j] + bb[cob + j], 0.f) * mk);
    *reinterpret_cast<half4*>(out + (long)v * C + cob) = r;
}

// ---- dense MFMA conv (r13-proven) + optional fused fp32 NCDHW output ----
template <int STRIDE, bool WF32>
__global__ __launch_bounds__(256) void mconv_kernel(
    const _Float16* __restrict__ in, _Float16* __restrict__ out,
    const float* __restrict__ mask, const _Float16* __restrict__ Whl,
    const float* __restrict__ bs, const float* __restrict__ bb,
    int Din, int Dout, float* __restrict__ outf) {
    int n = Dout * Dout * Dout;
    int tile = blockIdx.x * 4 + (threadIdx.x >> 6);
    if (tile * 16 >= n) return;

    int lane = threadIdx.x & 63;
    int col = lane & 15;
    int g = lane >> 4;
    int s = tile * 16 + col;
    bool val = s < n;
    int v = val ? s : 0;
    int x = v % Dout, y = (v / Dout) % Dout, z = v / (Dout * Dout);

    const half8* wf = reinterpret_cast<const half8*>(Whl);
    half8 a[NPAIR];
#pragma unroll
    for (int p = 0; p < NPAIR; p++) a[p] = wf[p * 64 + lane];

    int half_off = (g & 1) * 8;
    int tg = g >> 1;

    f32x4 acc = {0.f, 0.f, 0.f, 0.f};
#pragma unroll
    for (int p = 0; p < NPAIR; p++) {
        int tap = 2 * p + tg;
        if (tap > TAPS - 1) tap = TAPS - 1;
        int kz = tap / 9, ky = (tap / 3) % 3, kx = tap % 3;
        int zz = STRIDE * z - 1 + kz;
        int yy = STRIDE * y - 1 + ky;
        int xx = STRIDE * x - 1 + kx;
        bool ok = val && ((unsigned)zz < (unsigned)Din) && ((unsigned)yy < (unsigned)Din) &&
                  ((unsigned)xx < (unsigned)Din);
        half8 b = {};
        if (ok) {
            b = *reinterpret_cast<const half8*>(
                in + (long)((zz * Din + yy) * Din + xx) * C + half_off);
        }
        acc = __builtin_amdgcn_mfma_f32_16x16x32_f16(a[p], b, acc, 0, 0, 0);
    }

    if (val) {
        float mk = mask[v];
        int cob = g * 4;
        half4 r;
#pragma unroll
        for (int j = 0; j < 4; j++) {
            float t = fmaxf(acc[j] * bs[cob + j] + bb[cob + j], 0.f) * mk;
            r[j] = (_Float16)t;
            if (WF32) outf[(long)(cob + j) * n + v] = t;
        }
        *reinterpret_cast<half4*>(out + (long)v * C + cob) = r;
    }
}

// ---- fused 6^3 level: 4 conv layers, ONE block of 16 waves ----
__global__ __launch_bounds__(1024) void tail6_kernel(
    const _Float16* __restrict__ gin, const float* __restrict__ m6,
    const _Float16* __restrict__ Wh, const float* __restrict__ bs,
    const float* __restrict__ bb, float* __restrict__ out4) {
    __shared__ _Float16 G0[216 * 16], G1[216 * 16];
    __shared__ float Lm6[216];

    int tid = threadIdx.x;
    int lane = tid & 63;
    int wid = tid >> 6;
    int col = lane & 15, g = lane >> 4;
    int ho = (g & 1) * 8, tg = g >> 1;

    for (int i = tid; i < 216; i += 1024) Lm6[i] = m6[i];
    __syncthreads();

    int s = wid * 16 + col;
    bool val = (wid < 14) && (s < 216);
    int v = val ? s : 0;
    int x = v % 6, y = (v / 6) % 6, z = v / 36;

    auto layer = [&](const _Float16* gsrc, const _Float16* lsrc, int Din, int stride,
                     int lidx, _Float16* lout, float* outf) {
        const half8* wf = reinterpret_cast<const half8*>(Wh + (long)lidx * NPAIR * 64 * 8);
        half8 a[NPAIR];
#pragma unroll
        for (int p = 0; p < NPAIR; p++) a[p] = wf[p * 64 + lane];
        f32x4 acc = {0.f, 0.f, 0.f, 0.f};
#pragma unroll
        for (int p = 0; p < NPAIR; p++) {
            int tap = 2 * p + tg;
            if (tap > TAPS - 1) tap = TAPS - 1;
            int kz = tap / 9, ky = (tap / 3) % 3, kx = tap % 3;
            int zz = stride * z - 1 + kz;
            int yy = stride * y - 1 + ky;
            int xx = stride * x - 1 + kx;
            bool ok = val && ((unsigned)zz < (unsigned)Din) && ((unsigned)yy < (unsigned)Din) &&
                      ((unsigned)xx < (unsigned)Din);
            half8 b = {};
            if (ok) {
                long off = (long)((zz * Din + yy) * Din + xx) * C + ho;
                b = gsrc ? *reinterpret_cast<const half8*>(gsrc + off)
                         : *reinterpret_cast<const half8*>(lsrc + off);
            }
            acc = __builtin_amdgcn_mfma_f32_16x16x32_f16(a[p], b, acc, 0, 0, 0);
        }
        if (val) {
            float mkv = Lm6[v];
            int cob = g * 4;
            const float* bsl = bs + lidx * C;
            const float* bbl = bb + lidx * C;
            half4 r;
#pragma unroll
            for (int j = 0; j < 4; j++) {
                float t = fmaxf(acc[j] * bsl[cob + j] + bbl[cob + j], 0.f) * mkv;
                r[j] = (_Float16)t;
                if (outf) outf[(long)(cob + j) * 216 + v] = t;
            }
            if (lout) *reinterpret_cast<half4*>(lout + (long)v * C + cob) = r;
        }
        __syncthreads();
    };

    layer(gin, nullptr, 12, 2, 13, G0, nullptr);
    layer(nullptr, G0, 6, 1, 14, G1, nullptr);
    layer(nullptr, G1, 6, 1, 15, G0, nullptr);
    layer(nullptr, G0, 6, 1, 16, nullptr, out4);
}

extern "C" void kernel_launch(void* const* d_in, const int* in_sizes, int n_in,
                              void* d_out, int out_size, void* d_ws, size_t ws_size,
                              hipStream_t stream) {
    const float* x = (const float*)d_in[0];
    const int* mask_idx = (const int*)d_in[1];
    const float* W = (const float*)d_in[2];
    const float* bs = (const float*)d_in[3];
    const float* bb = (const float*)d_in[4];
    float* out = (float*)d_out;

    const int n96 = 96 * 96 * 96;
    const int n48 = 48 * 48 * 48;
    const int n24 = 24 * 24 * 24;
    const int n12 = 12 * 12 * 12;
    const int n6 = 6 * 6 * 6;
    const int NB = 3456;

    float* m48 = (float*)d_ws;
    float* m24 = m48 + n48;
    float* m12 = m24 + n24;
    float* m6 = m12 + n12;
    _Float16* Wh = (_Float16*)(m6 + n6);  // [17][14][64][8]
    int* list = (int*)(Wh + (long)NCONV * NPAIR * 64 * 8);
    int* counts = list + LISTCAP;
    int* offsets = counts + NB;
    int* nact = offsets + NB;
    int* inv = nact + 1;                    // n96 ints
    int* nbr = inv + n96;                   // 27*LISTCAP ints
    _Float16* Xc = (_Float16*)(nbr + TAPS * LISTCAP);
    _Float16* A1 = Xc + (long)LISTCAP * C;
    _Float16* A2 = A1 + (long)LISTCAP * C;
    _Float16* P0h = A2 + (long)LISTCAP * C;  // dense ping-pong (<= 48^3 * C)
    _Float16* P1h = P0h + (long)n48 * C;

    // 1. prep: weights + m48 + counts + inv=-1
    hipLaunchKernelGGL(prep_kernel, dim3(476 + 432 + 3456), dim3(256), 0, stream,
                       mask_idx, W, Wh, counts, m48, inv);
    // 2. scan
    hipLaunchKernelGGL(scan_kernel, dim3(1), dim3(256), 0, stream, counts, offsets, nact, NB);
    // 3. scatter (list+inv) + pools
    hipLaunchKernelGGL(scatter_kernel, dim3(3456 + 54 + 432 + 54), dim3(256), 0, stream,
                       mask_idx, offsets, list, inv, LISTCAP, m48, m24, m12, m6);
    // 4. compactx v2 (dense coalesced transpose + nbr table)
    hipLaunchKernelGGL(compactx_kernel, dim3(3456 + LISTCAP / 256), dim3(256), 0, stream,
                       x, list, nact, inv, Xc, nbr);

    auto mblk = [&](long nvox) { return dim3((unsigned)((nvox + 63) / 64)); };
    auto WL = [&](int l) { return Wh + (long)l * NPAIR * 64 * 8; };

    // 5-6. sparse 96 level (compacted)
    hipLaunchKernelGGL(sconv_kernel, mblk(LISTCAP), dim3(256), 0, stream,
                       Xc, A1, nbr, nact, WL(0), bs, bb);
    hipLaunchKernelGGL(sconv_kernel, mblk(LISTCAP), dim3(256), 0, stream,
                       A1, A2, nbr, nact, WL(1), bs + C, bb + C);
    // 7. down 96->48 via inv
    hipLaunchKernelGGL(dconv_inv_kernel, mblk(n48), dim3(256), 0, stream,
                       A2, P1h, m48, inv, WL(2), bs + 2 * C, bb + 2 * C);
    // 8-9. 48 level subm; L4 dual-writes net1
    hipLaunchKernelGGL((mconv_kernel<1, false>), mblk(n48), dim3(256), 0, stream,
                       P1h, P0h, m48, WL(3), bs + 3 * C, bb + 3 * C, 48, 48, (float*)nullptr);
    hipLaunchKernelGGL((mconv_kernel<1, true>), mblk(n48), dim3(256), 0, stream,
                       P0h, P1h, m48, WL(4), bs + 4 * C, bb + 4 * C, 48, 48, out);
    // 10-13. 24 level; L8 dual-writes net2
    hipLaunchKernelGGL((mconv_kernel<2, false>), mblk(n24), dim3(256), 0, stream,
                       P1h, P0h, m24, WL(5), bs + 5 * C, bb + 5 * C, 48, 24, (float*)nullptr);
    hipLaunchKernelGGL((mconv_kernel<1, false>), mblk(n24), dim3(256), 0, stream,
                       P0h, P1h, m24, WL(6), bs + 6 * C, bb + 6 * C, 24, 24, (float*)nullptr);
    hipLaunchKernelGGL((mconv_kernel<1, false>), mblk(n24), dim3(256), 0, stream,
                       P1h, P0h, m24, WL(7), bs + 7 * C, bb + 7 * C, 24, 24, (float*)nullptr);
    hipLaunchKernelGGL((mconv_kernel<1, true>), mblk(n24), dim3(256), 0, stream,
                       P0h, P1h, m24, WL(8), bs + 8 * C, bb + 8 * C, 24, 24, out + (long)C * n48);
    // 14-17. 12 level; L12 dual-writes net3
    hipLaunchKernelGGL((mconv_kernel<2, false>), mblk(n12), dim3(256), 0, stream,
                       P1h, P0h, m12, WL(9), bs + 9 * C, bb + 9 * C, 24, 12, (float*)nullptr);
    hipLaunchKernelGGL((mconv_kernel<1, false>), mblk(n12), dim3(256), 0, stream,
                       P0h, P1h, m12, WL(10), bs + 10 * C, bb + 10 * C, 12, 12, (float*)nullptr);
    hipLaunchKernelGGL((mconv_kernel<1, false>), mblk(n12), dim3(256), 0, stream,
                       P1h, P0h, m12, WL(11), bs + 11 * C, bb + 11 * C, 12, 12, (float*)nullptr);
    hipLaunchKernelGGL((mconv_kernel<1, true>), mblk(n12), dim3(256), 0, stream,
                       P0h, P1h, m12, WL(12), bs + 12 * C, bb + 12 * C, 12, 12,
                       out + (long)C * (n48 + n24));
    // 18. fused 6 level (layers 13-16; net4)
    hipLaunchKernelGGL(tail6_kernel, dim3(1), dim3(1024), 0, stream,
                       P1h, m6, Wh, bs, bb, out + (long)C * (n48 + n24 + n12));
}